// Round 3
// baseline (248.055 us; speedup 1.0000x reference)
//
#include <hip/hip_runtime.h>
#include <math.h>

#define L 2048
#define BATCH 8
#define RPS 16               // rows per block in stats kernel (4 waves x 4 rows)
#define NSPLIT (L / RPS)     // 128 column-partial slabs per batch
#define EPSF 1e-8f
#define C2 2.885390081777927f   // 2/ln2 : exp(2x) = exp2(x*C2)
#define C4 5.770780163555854f   // 4/ln2 : exp(4x) = exp2(x*C4)

typedef float f32x4 __attribute__((ext_vector_type(4)));

__device__ __forceinline__ float fexp2(float x) {
  return __builtin_amdgcn_exp2f(x);   // v_exp_f32
}
__device__ __forceinline__ float fsqrt(float x) {
  return __builtin_amdgcn_sqrtf(x);   // v_sqrt_f32 (~1.5 ulp, no fixup seq)
}

// Block = 256 threads (4 waves). Wave w owns rows i0+4w .. i0+4w+3 (whole rows).
// Per row: 8 unrolled steps of 1KB contiguous wave loads. Row sums accumulate in
// 4 per-lane registers (racc[0..3], static indices -> no scratch); ALL four
// shuffle butterflies are deferred to after the last load so the 6-step DS
// dependency chains overlap 4-wide instead of serializing between rows.
// Column sums are 32 per-lane registers (lane l, step s -> cols s*256 + 4l..+3),
// merged across the 4 waves once per block via LDS.
// sim loads here are NORMAL (cache-filling): they populate L3 so finalize_k's
// second read of sim can hit Infinity Cache instead of HBM. pcol is written
// non-temporally (single-use stream; don't displace sim from L2/L3).
__global__ __launch_bounds__(256) void stats_k(
    const float* __restrict__ sim, const int* __restrict__ lengths,
    float* __restrict__ rinv, float* __restrict__ pcol) {
  const int b = blockIdx.y;
  const int islab = blockIdx.x;
  const int len0 = lengths[2 * b], len1 = lengths[2 * b + 1];
  const int tid = threadIdx.x;
  const int wave = tid >> 6, lane = tid & 63;
  const int i0 = islab * RPS + wave * 4;
  const int jb = lane * 4;
  const int nrow = min(4, len0 - i0);  // may be <= 0: all rows masked

  float4 cacc[8];
#pragma unroll
  for (int s = 0; s < 8; ++s) cacc[s] = make_float4(0.f, 0.f, 0.f, 0.f);
  float racc[4] = {0.f, 0.f, 0.f, 0.f};

#pragma unroll
  for (int r = 0; r < 4; ++r) {
    if (r < nrow) {                    // wave-uniform; rows >= len0 contribute 0
      const float* p = sim + ((size_t)b * L + (i0 + r)) * L + jb;
      float acc = 0.f;
#pragma unroll
      for (int s = 0; s < 8; ++s) {
        float4 v = *reinterpret_cast<const float4*>(p + s * 256);
        float4 e;
        e.x = fexp2(v.x * C2); e.y = fexp2(v.y * C2);
        e.z = fexp2(v.z * C2); e.w = fexp2(v.w * C2);
        if (s >= 4) {                  // len1 >= 1024: steps 0-3 always valid
          const int j = s * 256 + jb;
          if (j + 0 >= len1) e.x = 0.f;
          if (j + 1 >= len1) e.y = 0.f;
          if (j + 2 >= len1) e.z = 0.f;
          if (j + 3 >= len1) e.w = 0.f;
        }
        acc += (e.x + e.y) + (e.z + e.w);
        cacc[s].x += e.x; cacc[s].y += e.y; cacc[s].z += e.z; cacc[s].w += e.w;
      }
      racc[r] = acc;
    }
  }

  // Deferred row reductions: 4 butterflies interleave (ILP), one bubble total.
#pragma unroll
  for (int r = 0; r < 4; ++r) {
    if (r < nrow) {
      float v = racc[r];
#pragma unroll
      for (int off = 1; off < 64; off <<= 1) v += __shfl_xor(v, off, 64);
      if (lane == 0) rinv[(size_t)b * L + (i0 + r)] = 1.0f / v;
    }
  }

  __shared__ float cpart[4][2048];     // 32 KB
#pragma unroll
  for (int s = 0; s < 8; ++s)
    *reinterpret_cast<float4*>(&cpart[wave][s * 256 + jb]) = cacc[s];
  __syncthreads();

#pragma unroll
  for (int h = 0; h < 2; ++h) {
    const int c = h * 1024 + tid * 4;
    float4 a0 = *reinterpret_cast<const float4*>(&cpart[0][c]);
    float4 a1 = *reinterpret_cast<const float4*>(&cpart[1][c]);
    float4 a2 = *reinterpret_cast<const float4*>(&cpart[2][c]);
    float4 a3 = *reinterpret_cast<const float4*>(&cpart[3][c]);
    f32x4 o;
    o.x = (a0.x + a1.x) + (a2.x + a3.x);
    o.y = (a0.y + a1.y) + (a2.y + a3.y);
    o.z = (a0.z + a1.z) + (a2.z + a3.z);
    o.w = (a0.w + a1.w) + (a2.w + a3.w);
    __builtin_nontemporal_store(
        o, reinterpret_cast<f32x4*>(&pcol[(size_t)(b * NSPLIT + islab) * L + c]));
  }
}

__global__ __launch_bounds__(128) void col_merge_k(
    const float* __restrict__ pcol, float* __restrict__ cinv) {
  const int idx = blockIdx.x * 128 + threadIdx.x;  // b*L + j
  const int b = idx >> 11, j = idx & (L - 1);
  const float* p = pcol + (size_t)b * NSPLIT * L + j;
  float s = 0.f;
#pragma unroll 16
  for (int c = 0; c < NSPLIT; ++c)
    s += __builtin_nontemporal_load(p + (size_t)c * L);  // single-use stream
  cinv[idx] = 1.0f / s;   // inf for j >= len1: discarded by finalize's select
}

// NT discipline: sim is DEAD after this kernel's read -> nontemporal load
// (evict-first after consumption). out is never re-read -> nontemporal store
// (do not let 134 MB of out displace sim's L3 lines mid-kernel; sim+out = 268 MB
// > 256 MB Infinity Cache, so normal writes force the sim re-read back to HBM).
__global__ __launch_bounds__(512) void finalize_k(
    const float* __restrict__ sim, const int* __restrict__ lengths,
    const float* __restrict__ rinv, const float* __restrict__ cinv,
    float* __restrict__ out) {
  const int row = blockIdx.x;          // b*L + i ; one block = one full row
  const int b = row >> 11, i = row & (L - 1);
  const int len0 = lengths[2 * b], len1 = lengths[2 * b + 1];
  const int j = threadIdx.x * 4;
  const size_t off = (size_t)row * L + j;
  f32x4 o;
  if (i >= len0) {                     // block-uniform branch: zero row
    o = (f32x4){0.f, 0.f, 0.f, 0.f};
  } else {
    const float ri = rinv[row];
    f32x4 v = __builtin_nontemporal_load(
        reinterpret_cast<const f32x4*>(sim + off));
    f32x4 ci = *reinterpret_cast<const f32x4*>(cinv + ((size_t)b << 11) + j);
    o.x = (j + 0 < len1) ? fsqrt(EPSF + fexp2(v.x * C4) * ri * ci.x) : 0.f;
    o.y = (j + 1 < len1) ? fsqrt(EPSF + fexp2(v.y * C4) * ri * ci.y) : 0.f;
    o.z = (j + 2 < len1) ? fsqrt(EPSF + fexp2(v.z * C4) * ri * ci.z) : 0.f;
    o.w = (j + 3 < len1) ? fsqrt(EPSF + fexp2(v.w * C4) * ri * ci.w) : 0.f;
  }
  __builtin_nontemporal_store(o, reinterpret_cast<f32x4*>(out + off));
}

extern "C" void kernel_launch(void* const* d_in, const int* in_sizes, int n_in,
                              void* d_out, int out_size, void* d_ws, size_t ws_size,
                              hipStream_t stream) {
  const float* sim = (const float*)d_in[0];
  const int* lengths = (const int*)d_in[1];
  float* out = (float*)d_out;
  float* ws = (float*)d_ws;

  const int NR = BATCH * L;  // 16384
  float* rinv = ws;
  float* cinv = ws + NR;
  float* pcol = ws + 2 * (size_t)NR;
  // ws use: 2*16384 + 8*128*2048 floats = ~8.1 MiB

  hipLaunchKernelGGL(stats_k, dim3(NSPLIT, BATCH), dim3(256), 0, stream,
                     sim, lengths, rinv, pcol);
  hipLaunchKernelGGL(col_merge_k, dim3(NR / 128), dim3(128), 0, stream,
                     pcol, cinv);
  hipLaunchKernelGGL(finalize_k, dim3(NR), dim3(512), 0, stream,
                     sim, lengths, rinv, cinv, out);
}